// Round 3
// baseline (864.173 us; speedup 1.0000x reference)
//
#include <hip/hip_runtime.h>
#include <hip/hip_bf16.h>
#include <stdint.h>

// Problem constants (from reference setup_inputs)
#define N_NODES 50000
#define NE      400000
#define HDIM    128
#define MPAD    50048     // 391 * 128, zero-padded rows for clean GEMM tiling
#define TE      128       // edges per block in edge kernel

typedef __attribute__((ext_vector_type(8))) short bf16x8;   // 8 bf16 in 4 VGPRs
typedef __attribute__((ext_vector_type(4))) float f32x4;

__device__ __forceinline__ ushort f2b(float f) {
    uint32_t u = __float_as_uint(f);
    uint32_t r = (u + 0x7fffu + ((u >> 16) & 1u)) >> 16;   // RTNE
    return (ushort)r;
}
__device__ __forceinline__ float b2f(ushort s) {
    return __uint_as_float(((uint32_t)s) << 16);
}
__device__ __forceinline__ float silu_f(float x) {
    return x / (1.f + __expf(-x));
}
__device__ __forceinline__ float tanh_f(float x) {
    return 1.f - 2.f / (__expf(2.f * x) + 1.f);
}

// ---------------------------------------------------------------------------
// out[0:NH) = x, out[NH:2NH) = pe   (baseline for deg-0 nodes + boundary atomics)
__global__ void k_init_out(const float4* __restrict__ x, const float4* __restrict__ pe,
                           float4* __restrict__ out) {
    int i = blockIdx.x * 256 + threadIdx.x;
    const int nh4 = N_NODES * HDIM / 4;
    if (i < nh4) out[i] = x[i];
    else out[i] = pe[i - nh4];
}

// Xc[row, 0:128] = bf16(x[row]), Xc[row,128:256] = bf16(pe[row]); pad rows = 0
__global__ void k_prep_xc(const float4* __restrict__ x, const float4* __restrict__ pe,
                          ushort* __restrict__ Xc) {
    int idx = blockIdx.x * 256 + threadIdx.x;
    int row = idx >> 6;
    int cq  = idx & 63;
    float4 v = make_float4(0.f, 0.f, 0.f, 0.f);
    if (row < N_NODES) v = (cq < 32) ? x[row * 32 + cq] : pe[row * 32 + (cq - 32)];
    ushort r[4] = { f2b(v.x), f2b(v.y), f2b(v.z), f2b(v.w) };
    *(uint2*)(Xc + (size_t)row * 256 + cq * 4) = *(const uint2*)r;
}

// Build transposed bf16 weights + dist-row extracts.
__global__ void k_prep_w(const float* __restrict__ W1, const float* __restrict__ Wp1,
                         const float* __restrict__ W2, const float* __restrict__ Wp2,
                         ushort* __restrict__ WcT, ushort* __restrict__ W2t,
                         ushort* __restrict__ Wp2t, float* __restrict__ w1d,
                         float* __restrict__ wp1d) {
    int b = blockIdx.x, t = threadIdx.x;
    if (b < 512) {
        int n = b, k = t;
        float v;
        if (n < 128)       v = W1[k * HDIM + n];
        else if (n < 256)  v = W1[(256 + k) * HDIM + (n - 128)];
        else if (n < 384)  v = (k < 128) ? 0.f : Wp1[(k - 128) * HDIM + (n - 256)];
        else               v = (k < 128) ? 0.f : Wp1[k * HDIM + (n - 384)];
        WcT[n * 256 + k] = f2b(v);
    } else if (b < 640) {
        if (t < 128) { int n = b - 512; W2t[n * HDIM + t] = f2b(W2[t * HDIM + n]); }
    } else if (b < 768) {
        if (t < 128) { int n = b - 640; Wp2t[n * HDIM + t] = f2b(Wp2[t * HDIM + n]); }
    } else {
        if (t < 128) w1d[t] = W1[512 * HDIM + t];
        else if (t < 256) wp1d[t - 128] = Wp1[256 * HDIM + (t - 128)];
    }
}

// ---------------------------------------------------------------------------
// Counting sort of edges by receiver node.
__global__ void k_hist(const int* __restrict__ eidx, int* __restrict__ cnt) {
    int e = blockIdx.x * 256 + threadIdx.x;
    if (e < NE) atomicAdd(&cnt[eidx[NE + e]], 1);
}

// Single-block exclusive scan of cnt[0..N) -> start[0..N], copy to cursor.
__global__ __launch_bounds__(1024) void k_scan(const int* __restrict__ cnt,
                                               int* __restrict__ start,
                                               int* __restrict__ cursor) {
    __shared__ int part[1024];
    const int CH = 49;                       // 1024*49 = 50176 >= 50000
    int tid = threadIdx.x;
    int lo = tid * CH, hi = min(lo + CH, N_NODES);
    int s = 0;
    for (int i = lo; i < hi; i++) s += cnt[i];
    part[tid] = s;
    __syncthreads();
    for (int off = 1; off < 1024; off <<= 1) {
        int v = (tid >= off) ? part[tid - off] : 0;
        __syncthreads();
        part[tid] += v;
        __syncthreads();
    }
    int run = tid ? part[tid - 1] : 0;       // exclusive base for this chunk
    for (int i = lo; i < hi; i++) {
        start[i] = run; cursor[i] = run;
        run += cnt[i];
    }
    if (tid == 1023) start[N_NODES] = part[1023];
}

__global__ void k_place(const int* __restrict__ eidx, int* __restrict__ cursor,
                        int* __restrict__ perm) {
    int e = blockIdx.x * 256 + threadIdx.x;
    if (e < NE) {
        int p = atomicAdd(&cursor[eidx[NE + e]], 1);
        perm[p] = e;
    }
}

// ---------------------------------------------------------------------------
// Pn[MPAD,512] bf16 = Xc[MPAD,256] @ Wc[256,512], via WcT.
__global__ __launch_bounds__(256) void k_node_gemm(const ushort* __restrict__ Xc,
                                                   const ushort* __restrict__ WcT,
                                                   ushort* __restrict__ Pn) {
    const int m0 = blockIdx.y * 128;
    const int n0 = blockIdx.x * 128;
    const int wave = threadIdx.x >> 6;
    const int lane = threadIdx.x & 63;
    const int l15 = lane & 15, quad = lane >> 4;
    const int qr = (wave >> 1) * 64, qc = (wave & 1) * 64;

    f32x4 acc[4][4];
#pragma unroll
    for (int i = 0; i < 4; i++)
#pragma unroll
        for (int j = 0; j < 4; j++) acc[i][j] = (f32x4){0.f, 0.f, 0.f, 0.f};

#pragma unroll
    for (int s = 0; s < 8; s++) {
        const int k0 = s * 32 + quad * 8;
        bf16x8 a[4], b[4];
#pragma unroll
        for (int rg = 0; rg < 4; rg++) {
            int row = m0 + qr + rg * 16 + l15;
            a[rg] = *(const bf16x8*)(Xc + row * 256 + k0);
        }
#pragma unroll
        for (int cg = 0; cg < 4; cg++) {
            int nn = n0 + qc + cg * 16 + l15;
            b[cg] = *(const bf16x8*)(WcT + nn * 256 + k0);
        }
#pragma unroll
        for (int rg = 0; rg < 4; rg++)
#pragma unroll
            for (int cg = 0; cg < 4; cg++)
                acc[rg][cg] = __builtin_amdgcn_mfma_f32_16x16x32_bf16(a[rg], b[cg], acc[rg][cg], 0, 0, 0);
    }

#pragma unroll
    for (int rg = 0; rg < 4; rg++)
#pragma unroll
        for (int cg = 0; cg < 4; cg++) {
            int col = n0 + qc + cg * 16 + l15;
            int rowb = m0 + qr + rg * 16 + quad * 4;
#pragma unroll
            for (int r = 0; r < 4; r++)
                Pn[(size_t)(rowb + r) * 512 + col] = f2b(acc[rg][cg][r]);
        }
}

// ---------------------------------------------------------------------------
// Edge kernel v3: edges pre-sorted by receiver (perm). grid (NE/TE, 2),
// blockIdx.y = path.  Per block: gather+layer1 -> sA, MFMA layer2, write msg
// bf16 back into sA, then segment-sum rows sharing the same receiver.
// Segments whose node lies entirely in this block -> plain store of
// base + sum; boundary segments (<=2/block) -> atomicAdd.
__global__ __launch_bounds__(256, 4) void k_edge(
    const ushort* __restrict__ Pn, const float* __restrict__ pos,
    const int* __restrict__ eidx, const int* __restrict__ perm,
    const int* __restrict__ startA, const int* __restrict__ cntA,
    const float* __restrict__ x, const float* __restrict__ pe,
    const float* __restrict__ w1d, const float* __restrict__ b1,
    const ushort* __restrict__ W2t, const float* __restrict__ b2,
    const float* __restrict__ wp1d, const float* __restrict__ bp1,
    const ushort* __restrict__ Wp2t, const float* __restrict__ bp2,
    float* __restrict__ out)
{
    __shared__ __align__(16) ushort sA[TE][136];   // h1 tile, then msg tile
    __shared__ float sDist[TE];
    __shared__ int sSend[TE], sRec[TE];
    __shared__ int sFlag[TE];                      // seg-start flags -> scan
    __shared__ int sSegStart[TE + 1];

    const int tid = threadIdx.x;
    const int e0 = blockIdx.x * TE;
    const int p  = blockIdx.y;

    const ushort* Wt = p ? Wp2t : W2t;
    const float* wd  = p ? wp1d : w1d;
    const float* bb1 = p ? bp1  : b1;
    const float* bb2 = p ? bp2  : b2;
    const float* basep = p ? pe : x;

    if (tid < TE) {
        int e = perm[e0 + tid];
        int s = eidx[e], r = eidx[NE + e];
        float dx = pos[s * 3 + 0] - pos[r * 3 + 0];
        float dy = pos[s * 3 + 1] - pos[r * 3 + 1];
        float dz = pos[s * 3 + 2] - pos[r * 3 + 2];
        sDist[tid] = sqrtf(dx * dx + dy * dy + dz * dz);
        sSend[tid] = s; sRec[tid] = r;
    }
    __syncthreads();

    // segment-start flags + inclusive scan (7 steps) -> segment ids
    if (tid < TE) sFlag[tid] = (tid == 0) || (sRec[tid] != sRec[tid - 1]);
    __syncthreads();
    for (int off = 1; off < TE; off <<= 1) {
        int v = (tid < TE && tid >= off) ? sFlag[tid - off] : 0;
        __syncthreads();
        if (tid < TE) sFlag[tid] += v;
        __syncthreads();
    }
    if (tid < TE && (tid == 0 || sFlag[tid] != sFlag[tid - 1]))
        sSegStart[sFlag[tid] - 1] = tid;
    if (tid == 0) sSegStart[sFlag[TE - 1]] = TE;

    // gather Pn halves, fuse first layer + activation, store bf16 tile
    for (int i = tid; i < TE * 16; i += 256) {
        int e = i >> 4, c8 = (i & 15) * 8;
        int s = sSend[e], r = sRec[e];
        float d = sDist[e];
        uint4 us = *(const uint4*)(Pn + (size_t)s * 512 + p * 256 + c8);
        uint4 ur = *(const uint4*)(Pn + (size_t)r * 512 + p * 256 + 128 + c8);
        const ushort* pus = (const ushort*)&us;
        const ushort* pur = (const ushort*)&ur;
        ushort res[8];
#pragma unroll
        for (int j = 0; j < 8; j++) {
            int ch = c8 + j;
            float v = b2f(pus[j]) + b2f(pur[j]) + d * wd[ch] + bb1[ch];
            v = p ? tanh_f(v) : silu_f(v);
            res[j] = f2b(v);
        }
        *(uint4*)&sA[e][c8] = *(const uint4*)res;
    }
    __syncthreads();

    const int wave = tid >> 6, lane = tid & 63;
    const int l15 = lane & 15, quad = lane >> 4;

    // MFMA: wave w covers edge rows [w*32, w*32+32).  B from global (L1/L2).
    f32x4 acc[2][8];
#pragma unroll
    for (int rg = 0; rg < 2; rg++)
#pragma unroll
        for (int cg = 0; cg < 8; cg++) acc[rg][cg] = (f32x4){0.f, 0.f, 0.f, 0.f};

#pragma unroll
    for (int s4 = 0; s4 < 4; s4++) {
        int k0 = s4 * 32 + quad * 8;
        bf16x8 a0 = *(const bf16x8*)&sA[wave * 32 + l15][k0];
        bf16x8 a1 = *(const bf16x8*)&sA[wave * 32 + 16 + l15][k0];
#pragma unroll
        for (int cg = 0; cg < 8; cg++) {
            bf16x8 b = *(const bf16x8*)(Wt + (cg * 16 + l15) * HDIM + k0);
            acc[0][cg] = __builtin_amdgcn_mfma_f32_16x16x32_bf16(a0, b, acc[0][cg], 0, 0, 0);
            acc[1][cg] = __builtin_amdgcn_mfma_f32_16x16x32_bf16(a1, b, acc[1][cg], 0, 0, 0);
        }
    }
    __syncthreads();   // all reads of sA (h1) complete

    // bias + activation, msg tile back into sA as bf16 (C-layout stores)
#pragma unroll
    for (int rg = 0; rg < 2; rg++) {
        int rowb = wave * 32 + rg * 16 + quad * 4;
#pragma unroll
        for (int cg = 0; cg < 8; cg++) {
            int col = cg * 16 + l15;
            float bias = bb2[col];
#pragma unroll
            for (int r = 0; r < 4; r++) {
                float v = acc[rg][cg][r] + bias;
                v = p ? tanh_f(v) : silu_f(v);
                sA[rowb + r][col] = f2b(v);
            }
        }
    }
    __syncthreads();

    // segment reduce: task = (segment, col-pair)
    const int nSeg = sFlag[TE - 1];
    float* outb = out + (size_t)p * N_NODES * HDIM;
    for (int task = tid; task < nSeg * 64; task += 256) {
        int seg = task >> 6, cp = task & 63;
        int r0 = sSegStart[seg], r1 = sSegStart[seg + 1];
        float a0 = 0.f, a1 = 0.f;
        for (int rr = r0; rr < r1; rr++) {
            unsigned int u = *(const unsigned int*)&sA[rr][cp * 2];
            a0 += b2f((ushort)(u & 0xffffu));
            a1 += b2f((ushort)(u >> 16));
        }
        int n = sRec[r0];
        int g0 = e0 + r0;
        bool interior = (g0 == startA[n]) && (g0 + (r1 - r0) == startA[n] + cntA[n]);
        float* op = outb + (size_t)n * HDIM + cp * 2;
        if (interior) {
            float2 bv = *(const float2*)(basep + (size_t)n * HDIM + cp * 2);
            *(float2*)op = make_float2(bv.x + a0, bv.y + a1);
        } else {
            atomicAdd(op, a0);
            atomicAdd(op + 1, a1);
        }
    }
}

// ---------------------------------------------------------------------------
extern "C" void kernel_launch(void* const* d_in, const int* in_sizes, int n_in,
                              void* d_out, int out_size, void* d_ws, size_t ws_size,
                              hipStream_t stream) {
    const float* x   = (const float*)d_in[0];
    const float* pos = (const float*)d_in[1];
    const float* pe  = (const float*)d_in[2];
    const int* eidx  = (const int*)d_in[3];
    const float* W1  = (const float*)d_in[4];
    const float* b1  = (const float*)d_in[5];
    const float* W2  = (const float*)d_in[6];
    const float* b2  = (const float*)d_in[7];
    const float* Wp1 = (const float*)d_in[8];
    const float* bp1 = (const float*)d_in[9];
    const float* Wp2 = (const float*)d_in[10];
    const float* bp2 = (const float*)d_in[11];
    float* out = (float*)d_out;

    // workspace carve-up (all offsets 256B aligned)
    char* w = (char*)d_ws;
    size_t off = 0;
    ushort* Xc   = (ushort*)(w + off); off += (size_t)MPAD * 256 * 2;   // 25,624,576
    ushort* Pn   = (ushort*)(w + off); off += (size_t)MPAD * 512 * 2;   // 51,249,152
    ushort* WcT  = (ushort*)(w + off); off += 512 * 256 * 2;            // 262,144
    ushort* W2t  = (ushort*)(w + off); off += 32768;
    ushort* Wp2t = (ushort*)(w + off); off += 32768;
    float*  w1d  = (float*)(w + off);  off += 2048;
    float*  wp1d = (float*)(w + off);  off += 2048;
    int* cnt     = (int*)(w + off);    off += 200704;                   // (N+1)*4 rounded
    int* startA  = (int*)(w + off);    off += 200704;
    int* cursor  = (int*)(w + off);    off += 200704;
    int* perm    = (int*)(w + off);    off += (size_t)NE * 4;           // 1,600,000

    // sort edges by receiver
    hipMemsetAsync(cnt, 0, (N_NODES + 1) * sizeof(int), stream);
    k_hist<<<(NE + 255) / 256, 256, 0, stream>>>(eidx, cnt);
    k_scan<<<1, 1024, 0, stream>>>(cnt, startA, cursor);
    k_place<<<(NE + 255) / 256, 256, 0, stream>>>(eidx, cursor, perm);

    // prep
    k_prep_w<<<769, 256, 0, stream>>>(W1, Wp1, W2, Wp2, WcT, W2t, Wp2t, w1d, wp1d);
    k_prep_xc<<<MPAD / 4, 256, 0, stream>>>((const float4*)x, (const float4*)pe, Xc);
    k_init_out<<<(2 * N_NODES * HDIM / 4 + 255) / 256, 256, 0, stream>>>(
        (const float4*)x, (const float4*)pe, (float4*)out);

    // node-level GEMM: Pn = Xc @ Wc
    dim3 ggrid(4, MPAD / 128);
    k_node_gemm<<<ggrid, 256, 0, stream>>>(Xc, WcT, Pn);

    // edge pipeline: sorted edges, in-block segment reduction
    dim3 egrid(NE / TE, 2);
    k_edge<<<egrid, 256, 0, stream>>>(Pn, pos, eidx, perm, startA, cnt, x, pe,
                                      w1d, b1, W2t, b2, wp1d, bp1, Wp2t, bp2, out);
}